// Round 5
// baseline (566.547 us; speedup 1.0000x reference)
//
#include <hip/hip_runtime.h>
#include <hip/hip_fp16.h>
#include <math.h>

#define GB 64        // graphs in batch
#define AD 8         // n_actions
#define NC2 1024     // edge chunks for hist/fill
#define BSH 6        // bucket shift -> bucket covers 64 consecutive dst nodes
#define BS  64       // bucket size (nodes)
#define NBMAX 1024   // max coarse buckets (n <= NBMAX*BS = 65536; also src packing needs n <= 65536)

// ---- pass 1: per-chunk LDS histogram of coarse bucket (dst>>6) ----
__global__ __launch_bounds__(256) void k_hist2(const int* __restrict__ ei,
                                               int* __restrict__ H2,
                                               int E, int ce, int NB) {
    __shared__ int h[NBMAX];
    int c = blockIdx.x;
    for (int b = threadIdx.x; b < NB; b += 256) h[b] = 0;
    __syncthreads();
    int e0 = c * ce, e1 = min(e0 + ce, E);
    for (int e = e0 + threadIdx.x; e < e1; e += 256)
        atomicAdd(&h[ei[E + e] >> BSH], 1);            // LDS atomic
    __syncthreads();
    for (int b = threadIdx.x; b < NB; b += 256)
        H2[(size_t)c * NB + b] = h[b];                 // coalesced
}

// ---- pass 2: per-bucket exclusive prefix across chunks (in place) + totals ----
__global__ __launch_bounds__(256) void k_cscan(int* __restrict__ H2,
                                               int* __restrict__ cntB,
                                               int NB, int nc) {
    int bin = blockIdx.x * 256 + threadIdx.x;
    if (bin >= NB) return;
    int s = 0;
    for (int c = 0; c < nc; c++) {
        size_t idx = (size_t)c * NB + bin;             // coalesced across threads
        int v = H2[idx];
        H2[idx] = s;
        s += v;
    }
    cntB[bin] = s;
}

// ---- pass 3: exclusive scan of bucket totals -> bb[]; sentinels ----
__global__ __launch_bounds__(1024) void k_bscan(const int* __restrict__ cntB,
                                                int* __restrict__ bb,
                                                int* __restrict__ rowptr,
                                                int NB, int n, int E) {
    __shared__ int sm[1024];
    int t = threadIdx.x;
    int v = (t < NB) ? cntB[t] : 0;
    sm[t] = v;
    __syncthreads();
    for (int s = 1; s < 1024; s <<= 1) {
        int tmp = (t >= s) ? sm[t - s] : 0;
        __syncthreads();
        sm[t] += tmp;
        __syncthreads();
    }
    if (t < NB) bb[t] = sm[t] - v;                     // exclusive
    if (t == NB - 1) bb[NB] = sm[t];                   // == E
    if (t == 0) rowptr[n] = E;                         // CSR sentinel
}

// ---- pass 4: edge MLP + scatter records into coarse buckets ----
// record: x = src | (dst_local << 16)  (needs n <= 65536), y = w (fp32 bits)
__global__ __launch_bounds__(256) void k_fill2(const int* __restrict__ ei,
                                               const float* __restrict__ attr,
                                               const float* __restrict__ W_e1,
                                               const float* __restrict__ b_e1,
                                               const float* __restrict__ W_e2,
                                               const float* __restrict__ b_e2,
                                               const int* __restrict__ bb,
                                               const int* __restrict__ H2,
                                               int2* __restrict__ rec,
                                               int E, int ce, int NB) {
    __shared__ int off[NBMAX];
    int c = blockIdx.x;
    for (int b = threadIdx.x; b < NB; b += 256)
        off[b] = bb[b] + H2[(size_t)c * NB + b];
    __syncthreads();
    float w1s = W_e1[0], w1d = W_e1[1], w1a = W_e1[2], bb1 = b_e1[0];
    float w2 = W_e2[0], bb2 = b_e2[0];
    int e0 = c * ce, e1 = min(e0 + ce, E);
    for (int e = e0 + threadIdx.x; e < e1; e += 256) {
        int d = ei[E + e];
        int s = ei[e];
        float h = fmaxf((float)s * w1s + (float)d * w1d + attr[e] * w1a + bb1, 0.0f);
        float w = 1.0f / (1.0f + expf(-(h * w2 + bb2)));
        int pos = atomicAdd(&off[d >> BSH], 1);        // LDS atomic
        int2 rv;
        rv.x = s | ((d & (BS - 1)) << 16);
        rv.y = __float_as_int(w);
        rec[pos] = rv;
    }
}

// ---- pass 5: per-bucket node sort + degree + dis + rowptr (fuses k_deg) ----
__global__ __launch_bounds__(256) void k_bucket(const int2* __restrict__ rec,
                                                const int* __restrict__ bb,
                                                int2* __restrict__ rec2,
                                                int* __restrict__ rowptr,
                                                float* __restrict__ dis, int n) {
    __shared__ int   cntL[BS];
    __shared__ float degL[BS];
    __shared__ int   pfx[BS];
    __shared__ int   cnt2[BS];
    int b = blockIdx.x;
    int t = threadIdx.x;
    if (t < BS) { cntL[t] = 0; degL[t] = 1.0f; cnt2[t] = 0; }   // deg starts at 1 (self-loop)
    __syncthreads();
    int s0 = bb[b], s1 = bb[b + 1];
    for (int j = s0 + t; j < s1; j += 256) {
        int2 rv = rec[j];
        int dl = (rv.x >> 16) & (BS - 1);
        atomicAdd(&cntL[dl], 1);
        atomicAdd(&degL[dl], __int_as_float(rv.y));    // LDS fp32 atomic
    }
    __syncthreads();
    if (t == 0) {
        int acc = 0;
        for (int k = 0; k < BS; k++) { pfx[k] = acc; acc += cntL[k]; }
    }
    __syncthreads();
    int lo = b << BSH;
    if (t < BS) {
        int i = lo + t;
        if (i < n) {
            rowptr[i] = s0 + pfx[t];
            dis[i] = rsqrtf(degL[t]);
        }
    }
    for (int j = s0 + t; j < s1; j += 256) {
        int2 rv = rec[j];
        int dl = (rv.x >> 16) & (BS - 1);
        int r = atomicAdd(&cnt2[dl], 1);
        int2 o;
        o.x = rv.x & 0xFFFF;
        o.y = rv.y;
        rec2[s0 + pfx[dl] + r] = o;                    // scatter within 16 KB window
    }
}

// ---- xw = x @ W_gcn, stored fp16 (M=50000, K=128, N=128) ----
__global__ __launch_bounds__(256) void k_xw(const float* __restrict__ x,
                                            const float* __restrict__ Wg,
                                            __half* __restrict__ xwh, int n) {
    __shared__ float xs[16 * 128];
    int block_row = blockIdx.x * 16;
    int tid = threadIdx.x;
    #pragma unroll
    for (int i = 0; i < 8; i++) {
        int idx = tid + i * 256;
        int r = idx >> 7, c = idx & 127;
        int gr = block_row + r;
        xs[idx] = (gr < n) ? x[(size_t)gr * 128 + c] : 0.0f;
    }
    __syncthreads();
    int c = tid & 127;
    int rbase = (tid >> 7) * 8;
    float acc[8] = {0, 0, 0, 0, 0, 0, 0, 0};
    for (int k = 0; k < 128; k++) {
        float wv = Wg[k * 128 + c];
        #pragma unroll
        for (int r = 0; r < 8; r++)
            acc[r] += xs[(rbase + r) * 128 + k] * wv;
    }
    #pragma unroll
    for (int r = 0; r < 8; r++) {
        int gr = block_row + rbase + r;
        if (gr < n) xwh[(size_t)gr * 128 + c] = __float2half(acc[r]);
    }
}

// ---- gather: one wave per node; lane owns half2 feature pair ----
__global__ __launch_bounds__(256) void k_gather(const int2* __restrict__ rec2,
                                                const int* __restrict__ rowptr,
                                                const float* __restrict__ dis,
                                                const __half2* __restrict__ xh,
                                                const float* __restrict__ bg,
                                                float* __restrict__ conv, int n) {
    int wave = threadIdx.x >> 6;
    int lane = threadIdx.x & 63;
    int i = blockIdx.x * 4 + wave;
    if (i >= n) return;                     // wave-uniform
    int st = rowptr[i];
    int m = rowptr[i + 1] - st;
    float di = dis[i];
    float2 self = __half22float2(xh[(size_t)i * 64 + lane]);
    float ax = di * self.x, ay = di * self.y;   // outer di applied at end
    for (int base = 0; base < m; base += 64) {
        int k = min(64, m - base);
        int sv = 0; float cf = 0.0f;
        if (lane < k) {
            int2 rv = rec2[st + base + lane];
            sv = rv.x;
            cf = __int_as_float(rv.y) * dis[rv.x];
        }
        #pragma unroll 4
        for (int j = 0; j < k; j++) {
            int s = __builtin_amdgcn_readlane(sv, j);
            float cw = __int_as_float(__builtin_amdgcn_readlane(__float_as_int(cf), j));
            float2 v = __half22float2(xh[(size_t)s * 64 + lane]);
            ax += cw * v.x;
            ay += cw * v.y;
        }
    }
    float2 bgl = ((const float2*)bg)[lane];
    float2 o;
    o.x = fmaxf(di * ax + bgl.x, 0.0f);
    o.y = fmaxf(di * ay + bgl.y, 0.0f);
    ((float2*)conv)[(size_t)i * 64 + lane] = o;
}

// ---- mean-pool: batch sorted -> running accumulate, flush on change ----
__global__ __launch_bounds__(128) void k_pool(const float* __restrict__ h1,
                                              const int* __restrict__ batch,
                                              float* __restrict__ psum,
                                              float* __restrict__ pcnt, int n) {
    int f = threadIdx.x;
    int n0 = blockIdx.x * 64;
    if (n0 >= n) return;
    int n1 = min(n0 + 64, n);
    int cur = batch[n0];
    float acc = 0.0f, cnt = 0.0f;
    for (int i = n0; i < n1; i++) {
        int g = batch[i];
        if (g != cur) {
            atomicAdd(&psum[cur * 128 + f], acc);
            if (f == 0) atomicAdd(&pcnt[cur], cnt);
            acc = 0.0f; cnt = 0.0f; cur = g;
        }
        acc += h1[(size_t)i * 128 + f];
        cnt += 1.0f;
    }
    atomicAdd(&psum[cur * 128 + f], acc);
    if (f == 0) atomicAdd(&pcnt[cur], cnt);
}

// ---- head: pooled = psum/cnt; h2 = relu(pooled@W2+b2); out = h2@W3+b3 ----
__global__ __launch_bounds__(128) void k_head(const float* __restrict__ psum,
                                              const float* __restrict__ pcnt,
                                              const float* __restrict__ W2,
                                              const float* __restrict__ b2,
                                              const float* __restrict__ W3,
                                              const float* __restrict__ b3,
                                              float* __restrict__ out) {
    __shared__ float pl[128];
    __shared__ float h2s[128];
    int g = blockIdx.x;
    int t = threadIdx.x;
    float c = fmaxf(pcnt[g], 1.0f);
    pl[t] = psum[g * 128 + t] / c;
    __syncthreads();
    float acc = b2[t];
    for (int k = 0; k < 128; k++) acc += pl[k] * W2[k * 128 + t];
    h2s[t] = fmaxf(acc, 0.0f);
    __syncthreads();
    if (t < AD) {
        float o = b3[t];
        for (int k = 0; k < 128; k++) o += h2s[k] * W3[k * AD + t];
        out[g * AD + t] = o;
    }
}

extern "C" void kernel_launch(void* const* d_in, const int* in_sizes, int n_in,
                              void* d_out, int out_size, void* d_ws, size_t ws_size,
                              hipStream_t stream) {
    const float* x        = (const float*)d_in[0];
    const float* edge_attr= (const float*)d_in[1];
    const float* W_e1     = (const float*)d_in[2];
    const float* b_e1     = (const float*)d_in[3];
    const float* W_e2     = (const float*)d_in[4];
    const float* b_e2     = (const float*)d_in[5];
    const float* W_gcn    = (const float*)d_in[6];
    const float* b_gcn    = (const float*)d_in[7];
    const float* W2       = (const float*)d_in[8];
    const float* b2       = (const float*)d_in[9];
    const float* W3       = (const float*)d_in[10];
    const float* b3       = (const float*)d_in[11];
    const int*   ei       = (const int*)d_in[12];
    const int*   batch    = (const int*)d_in[13];
    float* out = (float*)d_out;

    const int E  = in_sizes[12] / 2;          // 1,600,000
    const int n  = in_sizes[13];              // 50,000 (must be <= 65536 for packing)
    const int NB = (n + BS - 1) >> BSH;       // 782 coarse buckets
    const int ce = (E + NC2 - 1) / NC2;       // 1563 edges per chunk

    // workspace layout (~64.4 MB; conv region hosts H2, dead before gather)
    char* p = (char*)d_ws;
    __half* xwh   = (__half*)p;  p += (size_t)n * 128 * sizeof(__half);   // 12.8 MB
    int*    H2    = (int*)p;                                              // 3.2 MB, aliases conv
    float*  conv  = (float*)p;   p += (size_t)n * 128 * sizeof(float);    // 25.6 MB
    int2*   rec   = (int2*)p;    p += (size_t)E * sizeof(int2);           // 12.8 MB
    int2*   rec2  = (int2*)p;    p += (size_t)E * sizeof(int2);           // 12.8 MB
    float*  dis   = (float*)p;   p += (size_t)n * sizeof(float);
    float*  psum  = (float*)p;   p += (size_t)GB * 128 * sizeof(float);
    float*  pcnt  = (float*)p;   p += (size_t)GB * sizeof(float);
    int*    rowptr= (int*)p;     p += (size_t)(n + 1) * sizeof(int);
    int*    cntB  = (int*)p;     p += (size_t)NBMAX * sizeof(int);
    int*    bb    = (int*)p;     p += (size_t)(NBMAX + 1) * sizeof(int);

    hipMemsetAsync(psum, 0, (GB * 128 + GB) * sizeof(float), stream);

    k_xw<<<(n + 15) / 16, 256, 0, stream>>>(x, W_gcn, xwh, n);
    k_hist2<<<NC2, 256, 0, stream>>>(ei, H2, E, ce, NB);
    k_cscan<<<(NB + 255) / 256, 256, 0, stream>>>(H2, cntB, NB, NC2);
    k_bscan<<<1, 1024, 0, stream>>>(cntB, bb, rowptr, NB, n, E);
    k_fill2<<<NC2, 256, 0, stream>>>(ei, edge_attr, W_e1, b_e1, W_e2, b_e2,
                                     bb, H2, rec, E, ce, NB);
    k_bucket<<<NB, 256, 0, stream>>>(rec, bb, rec2, rowptr, dis, n);
    k_gather<<<(n + 3) / 4, 256, 0, stream>>>(rec2, rowptr, dis, (const __half2*)xwh,
                                              b_gcn, conv, n);
    k_pool<<<(n + 63) / 64, 128, 0, stream>>>(conv, batch, psum, pcnt, n);
    k_head<<<GB, 128, 0, stream>>>(psum, pcnt, W2, b2, W3, b3, out);
}

// Round 6
// 333.765 us; speedup vs baseline: 1.6974x; 1.6974x over previous
//
#include <hip/hip_runtime.h>
#include <hip/hip_fp16.h>
#include <math.h>

#define GB 64        // graphs in batch
#define AD 8         // n_actions
#define NC2 1024     // edge chunks for hist/fill
#define BSH 6        // bucket shift -> bucket covers 64 consecutive dst nodes
#define BS  64       // bucket size (nodes)
#define NBMAX 1024   // max coarse buckets (n <= NBMAX*BS = 65536; also src packing needs n <= 65536)

// ---- pass 1: per-chunk LDS histogram of coarse bucket (dst>>6) ----
__global__ __launch_bounds__(256) void k_hist2(const int* __restrict__ ei,
                                               int* __restrict__ H2,
                                               int E, int ce, int NB) {
    __shared__ int h[NBMAX];
    int c = blockIdx.x;
    for (int b = threadIdx.x; b < NB; b += 256) h[b] = 0;
    __syncthreads();
    int e0 = c * ce, e1 = min(e0 + ce, E);
    for (int e = e0 + threadIdx.x; e < e1; e += 256)
        atomicAdd(&h[ei[E + e] >> BSH], 1);            // LDS atomic
    __syncthreads();
    for (int b = threadIdx.x; b < NB; b += 256)
        H2[(size_t)c * NB + b] = h[b];                 // coalesced
}

// ---- pass 2: per-bucket exclusive prefix across chunks (one block per bucket) ----
__global__ __launch_bounds__(256) void k_cscan(int* __restrict__ H2,
                                               int* __restrict__ cntB,
                                               int NB, int nc) {
    __shared__ int ssum[256];
    int b = blockIdx.x;                    // bucket
    int t = threadIdx.x;
    int v[4];
    int local = 0;
    #pragma unroll
    for (int k = 0; k < 4; k++) {
        int c = t * 4 + k;                 // nc == 1024 == 256*4
        v[k] = (c < nc) ? H2[(size_t)c * NB + b] : 0;
        local += v[k];
    }
    ssum[t] = local;
    __syncthreads();
    for (int s = 1; s < 256; s <<= 1) {
        int tmp = (t >= s) ? ssum[t - s] : 0;
        __syncthreads();
        ssum[t] += tmp;
        __syncthreads();
    }
    int run = ssum[t] - local;             // exclusive prefix of this thread's group
    #pragma unroll
    for (int k = 0; k < 4; k++) {
        int c = t * 4 + k;
        if (c < nc) H2[(size_t)c * NB + b] = run;
        run += v[k];
    }
    if (t == 255) cntB[b] = ssum[255];
}

// ---- pass 3: exclusive scan of bucket totals -> bb[]; sentinels ----
__global__ __launch_bounds__(1024) void k_bscan(const int* __restrict__ cntB,
                                                int* __restrict__ bb,
                                                int* __restrict__ rowptr,
                                                int NB, int n, int E) {
    __shared__ int sm[1024];
    int t = threadIdx.x;
    int v = (t < NB) ? cntB[t] : 0;
    sm[t] = v;
    __syncthreads();
    for (int s = 1; s < 1024; s <<= 1) {
        int tmp = (t >= s) ? sm[t - s] : 0;
        __syncthreads();
        sm[t] += tmp;
        __syncthreads();
    }
    if (t < NB) bb[t] = sm[t] - v;                     // exclusive
    if (t == NB - 1) bb[NB] = sm[t];                   // == E
    if (t == 0) rowptr[n] = E;                         // CSR sentinel
}

// ---- pass 4: edge MLP + scatter records into coarse buckets ----
// record: x = src | (dst_local << 16)  (needs n <= 65536), y = w (fp32 bits)
__global__ __launch_bounds__(256) void k_fill2(const int* __restrict__ ei,
                                               const float* __restrict__ attr,
                                               const float* __restrict__ W_e1,
                                               const float* __restrict__ b_e1,
                                               const float* __restrict__ W_e2,
                                               const float* __restrict__ b_e2,
                                               const int* __restrict__ bb,
                                               const int* __restrict__ H2,
                                               int2* __restrict__ rec,
                                               int E, int ce, int NB) {
    __shared__ int off[NBMAX];
    int c = blockIdx.x;
    for (int b = threadIdx.x; b < NB; b += 256)
        off[b] = bb[b] + H2[(size_t)c * NB + b];
    __syncthreads();
    float w1s = W_e1[0], w1d = W_e1[1], w1a = W_e1[2], bb1 = b_e1[0];
    float w2 = W_e2[0], bb2 = b_e2[0];
    int e0 = c * ce, e1 = min(e0 + ce, E);
    for (int e = e0 + threadIdx.x; e < e1; e += 256) {
        int d = ei[E + e];
        int s = ei[e];
        float h = fmaxf((float)s * w1s + (float)d * w1d + attr[e] * w1a + bb1, 0.0f);
        float w = 1.0f / (1.0f + expf(-(h * w2 + bb2)));
        int pos = atomicAdd(&off[d >> BSH], 1);        // LDS atomic
        int2 rv;
        rv.x = s | ((d & (BS - 1)) << 16);
        rv.y = __float_as_int(w);
        rec[pos] = rv;
    }
}

// ---- pass 5: per-bucket node sort + degree + dis + rowptr (fuses k_deg) ----
__global__ __launch_bounds__(256) void k_bucket(const int2* __restrict__ rec,
                                                const int* __restrict__ bb,
                                                int2* __restrict__ rec2,
                                                int* __restrict__ rowptr,
                                                float* __restrict__ dis, int n) {
    __shared__ int   cntL[BS];
    __shared__ float degL[BS];
    __shared__ int   pfx[BS];
    __shared__ int   cnt2[BS];
    int b = blockIdx.x;
    int t = threadIdx.x;
    if (t < BS) { cntL[t] = 0; degL[t] = 1.0f; cnt2[t] = 0; }   // deg starts at 1 (self-loop)
    __syncthreads();
    int s0 = bb[b], s1 = bb[b + 1];
    for (int j = s0 + t; j < s1; j += 256) {
        int2 rv = rec[j];
        int dl = (rv.x >> 16) & (BS - 1);
        atomicAdd(&cntL[dl], 1);
        atomicAdd(&degL[dl], __int_as_float(rv.y));    // LDS fp32 atomic
    }
    __syncthreads();
    if (t == 0) {
        int acc = 0;
        for (int k = 0; k < BS; k++) { pfx[k] = acc; acc += cntL[k]; }
    }
    __syncthreads();
    int lo = b << BSH;
    if (t < BS) {
        int i = lo + t;
        if (i < n) {
            rowptr[i] = s0 + pfx[t];
            dis[i] = rsqrtf(degL[t]);
        }
    }
    for (int j = s0 + t; j < s1; j += 256) {
        int2 rv = rec[j];
        int dl = (rv.x >> 16) & (BS - 1);
        int r = atomicAdd(&cnt2[dl], 1);
        int2 o;
        o.x = rv.x & 0xFFFF;
        o.y = rv.y;
        rec2[s0 + pfx[dl] + r] = o;                    // scatter within 16 KB window
    }
}

// ---- xw = x @ W_gcn, stored fp16 (M=50000, K=128, N=128) ----
__global__ __launch_bounds__(256) void k_xw(const float* __restrict__ x,
                                            const float* __restrict__ Wg,
                                            __half* __restrict__ xwh, int n) {
    __shared__ float xs[16 * 128];
    int block_row = blockIdx.x * 16;
    int tid = threadIdx.x;
    #pragma unroll
    for (int i = 0; i < 8; i++) {
        int idx = tid + i * 256;
        int r = idx >> 7, c = idx & 127;
        int gr = block_row + r;
        xs[idx] = (gr < n) ? x[(size_t)gr * 128 + c] : 0.0f;
    }
    __syncthreads();
    int c = tid & 127;
    int rbase = (tid >> 7) * 8;
    float acc[8] = {0, 0, 0, 0, 0, 0, 0, 0};
    for (int k = 0; k < 128; k++) {
        float wv = Wg[k * 128 + c];
        #pragma unroll
        for (int r = 0; r < 8; r++)
            acc[r] += xs[(rbase + r) * 128 + k] * wv;
    }
    #pragma unroll
    for (int r = 0; r < 8; r++) {
        int gr = block_row + rbase + r;
        if (gr < n) xwh[(size_t)gr * 128 + c] = __float2half(acc[r]);
    }
}

// ---- gather: one wave per node; lane owns half2 feature pair ----
__global__ __launch_bounds__(256) void k_gather(const int2* __restrict__ rec2,
                                                const int* __restrict__ rowptr,
                                                const float* __restrict__ dis,
                                                const __half2* __restrict__ xh,
                                                const float* __restrict__ bg,
                                                float* __restrict__ conv, int n) {
    int wave = threadIdx.x >> 6;
    int lane = threadIdx.x & 63;
    int i = blockIdx.x * 4 + wave;
    if (i >= n) return;                     // wave-uniform
    int st = rowptr[i];
    int m = rowptr[i + 1] - st;
    float di = dis[i];
    float2 self = __half22float2(xh[(size_t)i * 64 + lane]);
    float ax = di * self.x, ay = di * self.y;   // outer di applied at end
    for (int base = 0; base < m; base += 64) {
        int k = min(64, m - base);
        int sv = 0; float cf = 0.0f;
        if (lane < k) {
            int2 rv = rec2[st + base + lane];
            sv = rv.x;
            cf = __int_as_float(rv.y) * dis[rv.x];
        }
        #pragma unroll 4
        for (int j = 0; j < k; j++) {
            int s = __builtin_amdgcn_readlane(sv, j);
            float cw = __int_as_float(__builtin_amdgcn_readlane(__float_as_int(cf), j));
            float2 v = __half22float2(xh[(size_t)s * 64 + lane]);
            ax += cw * v.x;
            ay += cw * v.y;
        }
    }
    float2 bgl = ((const float2*)bg)[lane];
    float2 o;
    o.x = fmaxf(di * ax + bgl.x, 0.0f);
    o.y = fmaxf(di * ay + bgl.y, 0.0f);
    ((float2*)conv)[(size_t)i * 64 + lane] = o;
}

// ---- mean-pool: batch sorted -> running accumulate, flush on change ----
__global__ __launch_bounds__(128) void k_pool(const float* __restrict__ h1,
                                              const int* __restrict__ batch,
                                              float* __restrict__ psum,
                                              float* __restrict__ pcnt, int n) {
    int f = threadIdx.x;
    int n0 = blockIdx.x * 64;
    if (n0 >= n) return;
    int n1 = min(n0 + 64, n);
    int cur = batch[n0];
    float acc = 0.0f, cnt = 0.0f;
    for (int i = n0; i < n1; i++) {
        int g = batch[i];
        if (g != cur) {
            atomicAdd(&psum[cur * 128 + f], acc);
            if (f == 0) atomicAdd(&pcnt[cur], cnt);
            acc = 0.0f; cnt = 0.0f; cur = g;
        }
        acc += h1[(size_t)i * 128 + f];
        cnt += 1.0f;
    }
    atomicAdd(&psum[cur * 128 + f], acc);
    if (f == 0) atomicAdd(&pcnt[cur], cnt);
}

// ---- head: pooled = psum/cnt; h2 = relu(pooled@W2+b2); out = h2@W3+b3 ----
__global__ __launch_bounds__(128) void k_head(const float* __restrict__ psum,
                                              const float* __restrict__ pcnt,
                                              const float* __restrict__ W2,
                                              const float* __restrict__ b2,
                                              const float* __restrict__ W3,
                                              const float* __restrict__ b3,
                                              float* __restrict__ out) {
    __shared__ float pl[128];
    __shared__ float h2s[128];
    int g = blockIdx.x;
    int t = threadIdx.x;
    float c = fmaxf(pcnt[g], 1.0f);
    pl[t] = psum[g * 128 + t] / c;
    __syncthreads();
    float acc = b2[t];
    for (int k = 0; k < 128; k++) acc += pl[k] * W2[k * 128 + t];
    h2s[t] = fmaxf(acc, 0.0f);
    __syncthreads();
    if (t < AD) {
        float o = b3[t];
        for (int k = 0; k < 128; k++) o += h2s[k] * W3[k * AD + t];
        out[g * AD + t] = o;
    }
}

extern "C" void kernel_launch(void* const* d_in, const int* in_sizes, int n_in,
                              void* d_out, int out_size, void* d_ws, size_t ws_size,
                              hipStream_t stream) {
    const float* x        = (const float*)d_in[0];
    const float* edge_attr= (const float*)d_in[1];
    const float* W_e1     = (const float*)d_in[2];
    const float* b_e1     = (const float*)d_in[3];
    const float* W_e2     = (const float*)d_in[4];
    const float* b_e2     = (const float*)d_in[5];
    const float* W_gcn    = (const float*)d_in[6];
    const float* b_gcn    = (const float*)d_in[7];
    const float* W2       = (const float*)d_in[8];
    const float* b2       = (const float*)d_in[9];
    const float* W3       = (const float*)d_in[10];
    const float* b3       = (const float*)d_in[11];
    const int*   ei       = (const int*)d_in[12];
    const int*   batch    = (const int*)d_in[13];
    float* out = (float*)d_out;

    const int E  = in_sizes[12] / 2;          // 1,600,000
    const int n  = in_sizes[13];              // 50,000 (must be <= 65536 for packing)
    const int NB = (n + BS - 1) >> BSH;       // 782 coarse buckets
    const int ce = (E + NC2 - 1) / NC2;       // 1563 edges per chunk

    // workspace layout (~64.4 MB; conv region hosts H2, dead before gather)
    char* p = (char*)d_ws;
    __half* xwh   = (__half*)p;  p += (size_t)n * 128 * sizeof(__half);   // 12.8 MB
    int*    H2    = (int*)p;                                              // 3.2 MB, aliases conv
    float*  conv  = (float*)p;   p += (size_t)n * 128 * sizeof(float);    // 25.6 MB
    int2*   rec   = (int2*)p;    p += (size_t)E * sizeof(int2);           // 12.8 MB
    int2*   rec2  = (int2*)p;    p += (size_t)E * sizeof(int2);           // 12.8 MB
    float*  dis   = (float*)p;   p += (size_t)n * sizeof(float);
    float*  psum  = (float*)p;   p += (size_t)GB * 128 * sizeof(float);
    float*  pcnt  = (float*)p;   p += (size_t)GB * sizeof(float);
    int*    rowptr= (int*)p;     p += (size_t)(n + 1) * sizeof(int);
    int*    cntB  = (int*)p;     p += (size_t)NBMAX * sizeof(int);
    int*    bb    = (int*)p;     p += (size_t)(NBMAX + 1) * sizeof(int);

    hipMemsetAsync(psum, 0, (GB * 128 + GB) * sizeof(float), stream);

    k_xw<<<(n + 15) / 16, 256, 0, stream>>>(x, W_gcn, xwh, n);
    k_hist2<<<NC2, 256, 0, stream>>>(ei, H2, E, ce, NB);
    k_cscan<<<NB, 256, 0, stream>>>(H2, cntB, NB, NC2);
    k_bscan<<<1, 1024, 0, stream>>>(cntB, bb, rowptr, NB, n, E);
    k_fill2<<<NC2, 256, 0, stream>>>(ei, edge_attr, W_e1, b_e1, W_e2, b_e2,
                                     bb, H2, rec, E, ce, NB);
    k_bucket<<<NB, 256, 0, stream>>>(rec, bb, rec2, rowptr, dis, n);
    k_gather<<<(n + 3) / 4, 256, 0, stream>>>(rec2, rowptr, dis, (const __half2*)xwh,
                                              b_gcn, conv, n);
    k_pool<<<(n + 63) / 64, 128, 0, stream>>>(conv, batch, psum, pcnt, n);
    k_head<<<GB, 128, 0, stream>>>(psum, pcnt, W2, b2, W3, b3, out);
}